// Round 4
// baseline (28363.889 us; speedup 1.0000x reference)
//
#include <hip/hip_runtime.h>
#include <math.h>

// LSTM_53171695124900: 2-layer LSTM, H=1024, I=64, O=2, T=4096.
// Persistent kernel, 256 WGs x 512 threads (1 WG/CU, 2 waves/SIMD).
// Round-4 change vs round-3 (27.2ms): weights as 24 named float4 SSA values
// instead of float[32] arrays. r1-r3 all had VGPR_Count < weight count ->
// the arrays were never SROA'd (variable index vs late unroll) and lived in
// SCRATCH for the whole kernel; every phase re-streamed ~48MB grid-wide from
// L2/L3 (FETCH 300MB, WRITE +48MB spill signature). Vector SSA values cannot
// be allocas -> guaranteed VGPR residency.

#define HID 1024
#define DIN 64
#define TSTEPS 4096
#define NWG 256
#define TPB 512

// ws layout (floats)
#define WS_H1 0              // 2 x 1024 (double-buffered h1)
#define WS_H2 2048           // 2 x 1024 (double-buffered h2)
#define WS_FLAGS 4096        // 256 uints (barrier phase flags)
#define WS_HIST 4352         // 4096 x 1024 h2 history (optional)
#define WS_ZERO_BYTES ((4096 + 256) * sizeof(float))
#define WS_HIST_BYTES ((size_t)(WS_HIST + (size_t)TSTEPS * HID) * sizeof(float))

__device__ __forceinline__ float sigmoid_f(float v) {
    return 1.0f / (1.0f + __expf(-v));
}
__device__ __forceinline__ float tanh_f(float v) {
    return 2.0f / (1.0f + __expf(-2.0f * v)) - 1.0f;
}

// relaxed agent-scope atomics: coherent at L3, bypass non-coherent L1/L2,
// no buffer_inv/buffer_wbl2 cache maintenance
__device__ __forceinline__ void st_agent(float* p, float v) {
    __hip_atomic_store(p, v, __ATOMIC_RELAXED, __HIP_MEMORY_SCOPE_AGENT);
}
__device__ __forceinline__ float ld_agent(const float* p) {
    return __hip_atomic_load(p, __ATOMIC_RELAXED, __HIP_MEMORY_SCOPE_AGENT);
}

// pin a float4's components into VGPRs (defeat remat; SSA so no alloca)
#define PIN4(v) asm volatile("" : "+v"((v).x), "+v"((v).y), "+v"((v).z), "+v"((v).w))

// one 4-element k-chunk: layer1 acc (a*) gets W1.hv; layer2 acc (e*) gets
// W2.hv + W3.gv
#define GSTEP(o, W1, W2, W3) do {                                   \
    float4 hv = *(const float4*)(hb + (o));                         \
    a0 = fmaf((W1).x, hv.x, a0); a1 = fmaf((W1).y, hv.y, a1);       \
    a2 = fmaf((W1).z, hv.z, a2); a3 = fmaf((W1).w, hv.w, a3);       \
    e0 = fmaf((W2).x, hv.x, e0); e1 = fmaf((W2).y, hv.y, e1);       \
    e2 = fmaf((W2).z, hv.z, e2); e3 = fmaf((W2).w, hv.w, e3);       \
    float4 gv = *(const float4*)(gb + (o));                         \
    e0 = fmaf((W3).x, gv.x, e0); e1 = fmaf((W3).y, gv.y, e1);       \
    e2 = fmaf((W3).z, gv.z, e2); e3 = fmaf((W3).w, gv.w, e3);       \
} while (0)

__global__ __launch_bounds__(TPB, 2) void lstm_persistent(
    const float* __restrict__ x,
    const float* __restrict__ Wih1, const float* __restrict__ Whh1,
    const float* __restrict__ bih1, const float* __restrict__ bhh1,
    const float* __restrict__ Wih2, const float* __restrict__ Whh2,
    const float* __restrict__ bih2, const float* __restrict__ bhh2,
    const float* __restrict__ Wout, const float* __restrict__ bout,
    float* __restrict__ out, float* __restrict__ ws, int use_hist)
{
    const int wg   = blockIdx.x;          // 0..255
    const int tid  = threadIdx.x;         // 0..511
    const int wave = tid >> 6;            // 0..7
    const int lane = tid & 63;
    const int gate = tid >> 7;            // 0..3 (i,f,g,o)
    const int rsub = (tid >> 5) & 3;      // local unit 0..3
    const int c    = tid & 31;            // k-chunk 0..31 (32 elems each)
    const int row  = gate * HID + (wg << 2) + rsub;   // gate row in [0,4096)
    const int kbase = c << 5;

    float* h1buf = ws + WS_H1;
    float* h2buf = ws + WS_H2;
    unsigned* flags = (unsigned*)(ws + WS_FLAGS);
    float* h2hist = ws + WS_HIST;

    // ---- persistent register weights: 24 named float4 SSA values ----
    const float4* p1 = (const float4*)(Whh1 + (size_t)row * HID + kbase);
    const float4* p2 = (const float4*)(Wih2 + (size_t)row * HID + kbase);
    const float4* p3 = (const float4*)(Whh2 + (size_t)row * HID + kbase);
    float4 w1a = p1[0], w1b = p1[1], w1c = p1[2], w1d = p1[3];
    float4 w1e = p1[4], w1f = p1[5], w1g = p1[6], w1h = p1[7];
    float4 w2a = p2[0], w2b = p2[1], w2c = p2[2], w2d = p2[3];
    float4 w2e = p2[4], w2f = p2[5], w2g = p2[6], w2h = p2[7];
    float4 w3a = p3[0], w3b = p3[1], w3c = p3[2], w3d = p3[3];
    float4 w3e = p3[4], w3f = p3[5], w3g = p3[6], w3h = p3[7];
    PIN4(w1a); PIN4(w1b); PIN4(w1c); PIN4(w1d);
    PIN4(w1e); PIN4(w1f); PIN4(w1g); PIN4(w1h);
    PIN4(w2a); PIN4(w2b); PIN4(w2c); PIN4(w2d);
    PIN4(w2e); PIN4(w2f); PIN4(w2g); PIN4(w2h);
    PIN4(w3a); PIN4(w3b); PIN4(w3c); PIN4(w3d);
    PIN4(w3e); PIN4(w3f); PIN4(w3g); PIN4(w3h);

    const float2 wx = *(const float2*)(Wih1 + (size_t)row * DIN + (c << 1));
    const float bsum1 = bih1[row] + bhh1[row];
    const float bsum2 = bih2[row] + bhh2[row];
    const float2 wo0 = *(const float2*)(Wout + (tid << 1));
    const float2 wo1 = *(const float2*)(Wout + HID + (tid << 1));
    const float bo0 = bout[0], bo1 = bout[1];

    // LDS: staged h vectors, stride-36 rows (32 data + 4 pad, 16B aligned)
    __shared__ __align__(16) float h1s[1152];
    __shared__ __align__(16) float h2s[1152];
    __shared__ float g1[4][4], g2[4][4];
    __shared__ float c1s[4], c2s[4];
    __shared__ float red0[8], red1[8];
    if (tid < 4) { c1s[tid] = 0.0f; c2s[tid] = 0.0f; }

    // element e=2*tid lands at 36*(e>>5) + (e&31)
    const int sdst = 36 * (tid >> 4) + ((tid << 1) & 31);
    const int sbase = 36 * c;

    for (int p = 0; p <= TSTEPS; ++p) {
        const int cur = p & 1, prv = cur ^ 1;

        // ---- stage h1(p-1), h2(p-2) (slot prv) into LDS ----
        const float* s1 = h1buf + prv * HID + (tid << 1);
        const float* s2 = h2buf + prv * HID + (tid << 1);
        float sa0 = ld_agent(s1 + 0), sa1 = ld_agent(s1 + 1);
        float sb0 = ld_agent(s2 + 0), sb1 = ld_agent(s2 + 1);
        *(float2*)(h1s + sdst) = make_float2(sa0, sa1);
        *(float2*)(h2s + sdst) = make_float2(sb0, sb1);

        // ---- fallback out-path: WG0 computes out(p-2) in-loop ----
        if (!use_hist && wg == 0 && p >= 2) {
            float q0 = wo0.x * sb0 + wo0.y * sb1;
            float q1 = wo1.x * sb0 + wo1.y * sb1;
            #pragma unroll
            for (int m = 1; m < 64; m <<= 1) {
                q0 += __shfl_xor(q0, m);
                q1 += __shfl_xor(q1, m);
            }
            if (lane == 0) { red0[wave] = q0; red1[wave] = q1; }
            __syncthreads();
            if (tid == 0) {
                float o0 = bo0, o1 = bo1;
                #pragma unroll
                for (int w = 0; w < 8; ++w) { o0 += red0[w]; o1 += red1[w]; }
                out[2*(p-2)+0] = o0;
                out[2*(p-2)+1] = o1;
            }
        }
        __syncthreads();

        // ---- dots: a* = Whh1 . h1prev (+ x)       [layer 1, t=p]
        //            e* = Wih2 . h1prev + Whh2 . h2prev [layer 2, t=p-1]
        float a0=0.f, a1=0.f, a2=0.f, a3=0.f;
        float e0=0.f, e1=0.f, e2=0.f, e3=0.f;
        const float* hb = h1s + sbase;
        const float* gb = h2s + sbase;
        GSTEP(0,  w1a, w2a, w3a);
        GSTEP(4,  w1b, w2b, w3b);
        GSTEP(8,  w1c, w2c, w3c);
        GSTEP(12, w1d, w2d, w3d);
        GSTEP(16, w1e, w2e, w3e);
        GSTEP(20, w1f, w2f, w3f);
        GSTEP(24, w1g, w2g, w3g);
        GSTEP(28, w1h, w2h, w3h);
        {
            const int tx = (p < TSTEPS) ? p : 0;
            const float2 xv = *(const float2*)(x + (size_t)tx * DIN + (c << 1));
            a0 = fmaf(wx.x, xv.x, a0);
            a1 = fmaf(wx.y, xv.y, a1);
        }
        float accA = (a0 + a1) + (a2 + a3);
        float accB = (e0 + e1) + (e2 + e3);
        accA += __shfl_xor(accA, 1);   accB += __shfl_xor(accB, 1);
        accA += __shfl_xor(accA, 2);   accB += __shfl_xor(accB, 2);
        accA += __shfl_xor(accA, 4);   accB += __shfl_xor(accB, 4);
        accA += __shfl_xor(accA, 8);   accB += __shfl_xor(accB, 8);
        accA += __shfl_xor(accA, 16);  accB += __shfl_xor(accB, 16);
        if (c == 0) {
            float vA = accA + bsum1;
            float vB = accB + bsum2;
            g1[gate][rsub] = (gate == 2) ? tanh_f(vA) : sigmoid_f(vA);
            g2[gate][rsub] = (gate == 2) ? tanh_f(vB) : sigmoid_f(vB);
        }
        __syncthreads();

        // ---- state updates + h publication ----
        if (p < TSTEPS && tid < 4) {
            float iv = g1[0][tid], fv = g1[1][tid];
            float gv = g1[2][tid], ov = g1[3][tid];
            float cn = fv * c1s[tid] + iv * gv;
            c1s[tid] = cn;
            st_agent(h1buf + cur * HID + (wg << 2) + tid, ov * tanh_f(cn));
        }
        if (p >= 1 && tid >= 4 && tid < 8) {
            int u = tid - 4;
            float iv = g2[0][u], fv = g2[1][u];
            float gv = g2[2][u], ov = g2[3][u];
            float cn = fv * c2s[u] + iv * gv;
            c2s[u] = cn;
            float hn = ov * tanh_f(cn);
            st_agent(h2buf + cur * HID + (wg << 2) + u, hn);
            if (use_hist)
                st_agent(h2hist + (size_t)(p - 1) * HID + (wg << 2) + u, hn);
        }

        // ---- fence-free grid barrier (publish p+1) ----
        // producer order: h stores -> vmcnt(0) -> flag store (all in wave 0)
        asm volatile("s_waitcnt vmcnt(0)" ::: "memory");
        if (tid == 0) {
            __hip_atomic_store(&flags[wg], (unsigned)(p + 1),
                               __ATOMIC_RELAXED, __HIP_MEMORY_SCOPE_AGENT);
        }
        {
            int guard = 0;
            while (__hip_atomic_load(&flags[tid & 255], __ATOMIC_RELAXED,
                                     __HIP_MEMORY_SCOPE_AGENT) < (unsigned)(p + 1)) {
                if (++guard > (1 << 17)) break;  // hang insurance only
            }
        }
        asm volatile("" ::: "memory");
        __syncthreads();   // also protects LDS reuse next phase
    }

    // ---- epilogue ----
    if (use_hist) {
        // WG w computes out[16w .. 16w+16): 2x 1024-dot per t across 512 thr
        for (int i = 0; i < 16; ++i) {
            const int t = (wg << 4) + i;
            const float* hp = h2hist + (size_t)t * HID + (tid << 1);
            float hv0 = ld_agent(hp + 0), hv1 = ld_agent(hp + 1);
            float q0 = wo0.x * hv0 + wo0.y * hv1;
            float q1 = wo1.x * hv0 + wo1.y * hv1;
            #pragma unroll
            for (int m = 1; m < 64; m <<= 1) {
                q0 += __shfl_xor(q0, m);
                q1 += __shfl_xor(q1, m);
            }
            if (lane == 0) { red0[wave] = q0; red1[wave] = q1; }
            __syncthreads();
            if (tid == 0) {
                float o0 = bo0, o1 = bo1;
                #pragma unroll
                for (int w = 0; w < 8; ++w) { o0 += red0[w]; o1 += red1[w]; }
                out[2*t+0] = o0;
                out[2*t+1] = o1;
            }
            __syncthreads();
        }
    } else if (wg == 0) {
        // out[T-1]: h2(T-1) lives in slot TSTEPS&1 == 0
        const float* hp = h2buf + (TSTEPS & 1) * HID + (tid << 1);
        float hv0 = ld_agent(hp + 0), hv1 = ld_agent(hp + 1);
        float q0 = wo0.x * hv0 + wo0.y * hv1;
        float q1 = wo1.x * hv0 + wo1.y * hv1;
        #pragma unroll
        for (int m = 1; m < 64; m <<= 1) {
            q0 += __shfl_xor(q0, m);
            q1 += __shfl_xor(q1, m);
        }
        if (lane == 0) { red0[wave] = q0; red1[wave] = q1; }
        __syncthreads();
        if (tid == 0) {
            float o0 = bo0, o1 = bo1;
            #pragma unroll
            for (int w = 0; w < 8; ++w) { o0 += red0[w]; o1 += red1[w]; }
            out[2*(TSTEPS-1)+0] = o0;
            out[2*(TSTEPS-1)+1] = o1;
        }
    }
}

extern "C" void kernel_launch(void* const* d_in, const int* in_sizes, int n_in,
                              void* d_out, int out_size, void* d_ws, size_t ws_size,
                              hipStream_t stream)
{
    const float* x    = (const float*)d_in[0];
    const float* Wih1 = (const float*)d_in[1];
    const float* Whh1 = (const float*)d_in[2];
    const float* bih1 = (const float*)d_in[3];
    const float* bhh1 = (const float*)d_in[4];
    const float* Wih2 = (const float*)d_in[5];
    const float* Whh2 = (const float*)d_in[6];
    const float* bih2 = (const float*)d_in[7];
    const float* bhh2 = (const float*)d_in[8];
    const float* Wout = (const float*)d_in[9];
    const float* bout = (const float*)d_in[10];
    float* out = (float*)d_out;
    float* ws  = (float*)d_ws;

    const int use_hist = (ws_size >= WS_HIST_BYTES) ? 1 : 0;

    // zero h-state + barrier flags (ws re-poisoned 0xAA before every call)
    hipMemsetAsync(d_ws, 0, WS_ZERO_BYTES, stream);

    hipLaunchKernelGGL(lstm_persistent, dim3(NWG), dim3(TPB), 0, stream,
                       x, Wih1, Whh1, bih1, bhh1,
                       Wih2, Whh2, bih2, bhh2,
                       Wout, bout, out, ws, use_hist);
}

// Round 5
// 25584.531 us; speedup vs baseline: 1.1086x; 1.1086x over previous
//
#include <hip/hip_runtime.h>
#include <math.h>

// LSTM_53171695124900: 2-layer LSTM, H=1024, I=64, O=2, T=4096.
// Persistent kernel, 256 WGs x 512 threads (1 WG/CU, 2 waves/SIMD).
// Round-5 change vs round-4 (28.4ms): clamp occupancy with
// amdgpu_waves_per_eu(2,2). __launch_bounds__(512,2) only sets a MIN
// waves/EU; the max-occupancy scheduler kept targeting 6 waves/EU
// (VGPR_Count=84 = floor(512/6) granule boundary) and spilled all 96
// weight floats to scratch every round (r2-r4: VGPR 140/92/84, ~5us/phase
// of L2/L3 scratch reloads). With max=2 the allocator budget is 256 VGPRs
// -> weights actually live in registers. Everything else identical to r4.

#define HID 1024
#define DIN 64
#define TSTEPS 4096
#define NWG 256
#define TPB 512

// ws layout (floats)
#define WS_H1 0              // 2 x 1024 (double-buffered h1)
#define WS_H2 2048           // 2 x 1024 (double-buffered h2)
#define WS_FLAGS 4096        // 256 uints (barrier phase flags)
#define WS_HIST 4352         // 4096 x 1024 h2 history (optional)
#define WS_ZERO_BYTES ((4096 + 256) * sizeof(float))
#define WS_HIST_BYTES ((size_t)(WS_HIST + (size_t)TSTEPS * HID) * sizeof(float))

__device__ __forceinline__ float sigmoid_f(float v) {
    return 1.0f / (1.0f + __expf(-v));
}
__device__ __forceinline__ float tanh_f(float v) {
    return 2.0f / (1.0f + __expf(-2.0f * v)) - 1.0f;
}

// relaxed agent-scope atomics: coherent at L3, bypass non-coherent L1/L2,
// no buffer_inv/buffer_wbl2 cache maintenance
__device__ __forceinline__ void st_agent(float* p, float v) {
    __hip_atomic_store(p, v, __ATOMIC_RELAXED, __HIP_MEMORY_SCOPE_AGENT);
}
__device__ __forceinline__ float ld_agent(const float* p) {
    return __hip_atomic_load(p, __ATOMIC_RELAXED, __HIP_MEMORY_SCOPE_AGENT);
}

// pin a float4's components into VGPRs (defeat remat/sinking; SSA, no alloca)
#define PIN4(v) asm volatile("" : "+v"((v).x), "+v"((v).y), "+v"((v).z), "+v"((v).w))

// one 4-element k-chunk: layer1 acc (a*) gets W1.hv; layer2 acc (e*) gets
// W2.hv + W3.gv
#define GSTEP(o, W1, W2, W3) do {                                   \
    float4 hv = *(const float4*)(hb + (o));                         \
    a0 = fmaf((W1).x, hv.x, a0); a1 = fmaf((W1).y, hv.y, a1);       \
    a2 = fmaf((W1).z, hv.z, a2); a3 = fmaf((W1).w, hv.w, a3);       \
    e0 = fmaf((W2).x, hv.x, e0); e1 = fmaf((W2).y, hv.y, e1);       \
    e2 = fmaf((W2).z, hv.z, e2); e3 = fmaf((W2).w, hv.w, e3);       \
    float4 gv = *(const float4*)(gb + (o));                         \
    e0 = fmaf((W3).x, gv.x, e0); e1 = fmaf((W3).y, gv.y, e1);       \
    e2 = fmaf((W3).z, gv.z, e2); e3 = fmaf((W3).w, gv.w, e3);       \
} while (0)

__global__ void
__attribute__((amdgpu_flat_work_group_size(TPB, TPB), amdgpu_waves_per_eu(2, 2)))
lstm_persistent(
    const float* __restrict__ x,
    const float* __restrict__ Wih1, const float* __restrict__ Whh1,
    const float* __restrict__ bih1, const float* __restrict__ bhh1,
    const float* __restrict__ Wih2, const float* __restrict__ Whh2,
    const float* __restrict__ bih2, const float* __restrict__ bhh2,
    const float* __restrict__ Wout, const float* __restrict__ bout,
    float* __restrict__ out, float* __restrict__ ws, int use_hist)
{
    const int wg   = blockIdx.x;          // 0..255
    const int tid  = threadIdx.x;         // 0..511
    const int wave = tid >> 6;            // 0..7
    const int lane = tid & 63;
    const int gate = tid >> 7;            // 0..3 (i,f,g,o)
    const int rsub = (tid >> 5) & 3;      // local unit 0..3
    const int c    = tid & 31;            // k-chunk 0..31 (32 elems each)
    const int row  = gate * HID + (wg << 2) + rsub;   // gate row in [0,4096)
    const int kbase = c << 5;

    float* h1buf = ws + WS_H1;
    float* h2buf = ws + WS_H2;
    unsigned* flags = (unsigned*)(ws + WS_FLAGS);
    float* h2hist = ws + WS_HIST;

    // ---- persistent register weights: 24 named float4 SSA values ----
    const float4* p1 = (const float4*)(Whh1 + (size_t)row * HID + kbase);
    const float4* p2 = (const float4*)(Wih2 + (size_t)row * HID + kbase);
    const float4* p3 = (const float4*)(Whh2 + (size_t)row * HID + kbase);
    float4 w1a = p1[0], w1b = p1[1], w1c = p1[2], w1d = p1[3];
    float4 w1e = p1[4], w1f = p1[5], w1g = p1[6], w1h = p1[7];
    float4 w2a = p2[0], w2b = p2[1], w2c = p2[2], w2d = p2[3];
    float4 w2e = p2[4], w2f = p2[5], w2g = p2[6], w2h = p2[7];
    float4 w3a = p3[0], w3b = p3[1], w3c = p3[2], w3d = p3[3];
    float4 w3e = p3[4], w3f = p3[5], w3g = p3[6], w3h = p3[7];
    PIN4(w1a); PIN4(w1b); PIN4(w1c); PIN4(w1d);
    PIN4(w1e); PIN4(w1f); PIN4(w1g); PIN4(w1h);
    PIN4(w2a); PIN4(w2b); PIN4(w2c); PIN4(w2d);
    PIN4(w2e); PIN4(w2f); PIN4(w2g); PIN4(w2h);
    PIN4(w3a); PIN4(w3b); PIN4(w3c); PIN4(w3d);
    PIN4(w3e); PIN4(w3f); PIN4(w3g); PIN4(w3h);

    const float2 wx = *(const float2*)(Wih1 + (size_t)row * DIN + (c << 1));
    const float bsum1 = bih1[row] + bhh1[row];
    const float bsum2 = bih2[row] + bhh2[row];
    const float2 wo0 = *(const float2*)(Wout + (tid << 1));
    const float2 wo1 = *(const float2*)(Wout + HID + (tid << 1));
    const float bo0 = bout[0], bo1 = bout[1];

    // LDS: staged h vectors, stride-36 rows (32 data + 4 pad, 16B aligned)
    __shared__ __align__(16) float h1s[1152];
    __shared__ __align__(16) float h2s[1152];
    __shared__ float g1[4][4], g2[4][4];
    __shared__ float c1s[4], c2s[4];
    __shared__ float red0[8], red1[8];
    if (tid < 4) { c1s[tid] = 0.0f; c2s[tid] = 0.0f; }

    // element e=2*tid lands at 36*(e>>5) + (e&31)
    const int sdst = 36 * (tid >> 4) + ((tid << 1) & 31);
    const int sbase = 36 * c;

    for (int p = 0; p <= TSTEPS; ++p) {
        const int cur = p & 1, prv = cur ^ 1;

        // ---- stage h1(p-1), h2(p-2) (slot prv) into LDS ----
        const float* s1 = h1buf + prv * HID + (tid << 1);
        const float* s2 = h2buf + prv * HID + (tid << 1);
        float sa0 = ld_agent(s1 + 0), sa1 = ld_agent(s1 + 1);
        float sb0 = ld_agent(s2 + 0), sb1 = ld_agent(s2 + 1);
        *(float2*)(h1s + sdst) = make_float2(sa0, sa1);
        *(float2*)(h2s + sdst) = make_float2(sb0, sb1);

        // ---- fallback out-path: WG0 computes out(p-2) in-loop ----
        if (!use_hist && wg == 0 && p >= 2) {
            float q0 = wo0.x * sb0 + wo0.y * sb1;
            float q1 = wo1.x * sb0 + wo1.y * sb1;
            #pragma unroll
            for (int m = 1; m < 64; m <<= 1) {
                q0 += __shfl_xor(q0, m);
                q1 += __shfl_xor(q1, m);
            }
            if (lane == 0) { red0[wave] = q0; red1[wave] = q1; }
            __syncthreads();
            if (tid == 0) {
                float o0 = bo0, o1 = bo1;
                #pragma unroll
                for (int w = 0; w < 8; ++w) { o0 += red0[w]; o1 += red1[w]; }
                out[2*(p-2)+0] = o0;
                out[2*(p-2)+1] = o1;
            }
        }
        __syncthreads();

        // ---- dots: a* = Whh1 . h1prev (+ x)       [layer 1, t=p]
        //            e* = Wih2 . h1prev + Whh2 . h2prev [layer 2, t=p-1]
        float a0=0.f, a1=0.f, a2=0.f, a3=0.f;
        float e0=0.f, e1=0.f, e2=0.f, e3=0.f;
        const float* hb = h1s + sbase;
        const float* gb = h2s + sbase;
        GSTEP(0,  w1a, w2a, w3a);
        GSTEP(4,  w1b, w2b, w3b);
        GSTEP(8,  w1c, w2c, w3c);
        GSTEP(12, w1d, w2d, w3d);
        GSTEP(16, w1e, w2e, w3e);
        GSTEP(20, w1f, w2f, w3f);
        GSTEP(24, w1g, w2g, w3g);
        GSTEP(28, w1h, w2h, w3h);
        {
            const int tx = (p < TSTEPS) ? p : 0;
            const float2 xv = *(const float2*)(x + (size_t)tx * DIN + (c << 1));
            a0 = fmaf(wx.x, xv.x, a0);
            a1 = fmaf(wx.y, xv.y, a1);
        }
        float accA = (a0 + a1) + (a2 + a3);
        float accB = (e0 + e1) + (e2 + e3);
        accA += __shfl_xor(accA, 1);   accB += __shfl_xor(accB, 1);
        accA += __shfl_xor(accA, 2);   accB += __shfl_xor(accB, 2);
        accA += __shfl_xor(accA, 4);   accB += __shfl_xor(accB, 4);
        accA += __shfl_xor(accA, 8);   accB += __shfl_xor(accB, 8);
        accA += __shfl_xor(accA, 16);  accB += __shfl_xor(accB, 16);
        if (c == 0) {
            float vA = accA + bsum1;
            float vB = accB + bsum2;
            g1[gate][rsub] = (gate == 2) ? tanh_f(vA) : sigmoid_f(vA);
            g2[gate][rsub] = (gate == 2) ? tanh_f(vB) : sigmoid_f(vB);
        }
        __syncthreads();

        // ---- state updates + h publication ----
        if (p < TSTEPS && tid < 4) {
            float iv = g1[0][tid], fv = g1[1][tid];
            float gv = g1[2][tid], ov = g1[3][tid];
            float cn = fv * c1s[tid] + iv * gv;
            c1s[tid] = cn;
            st_agent(h1buf + cur * HID + (wg << 2) + tid, ov * tanh_f(cn));
        }
        if (p >= 1 && tid >= 4 && tid < 8) {
            int u = tid - 4;
            float iv = g2[0][u], fv = g2[1][u];
            float gv = g2[2][u], ov = g2[3][u];
            float cn = fv * c2s[u] + iv * gv;
            c2s[u] = cn;
            float hn = ov * tanh_f(cn);
            st_agent(h2buf + cur * HID + (wg << 2) + u, hn);
            if (use_hist)
                st_agent(h2hist + (size_t)(p - 1) * HID + (wg << 2) + u, hn);
        }

        // ---- fence-free grid barrier (publish p+1) ----
        // producer order: h stores -> vmcnt(0) -> flag store (all in wave 0)
        asm volatile("s_waitcnt vmcnt(0)" ::: "memory");
        if (tid == 0) {
            __hip_atomic_store(&flags[wg], (unsigned)(p + 1),
                               __ATOMIC_RELAXED, __HIP_MEMORY_SCOPE_AGENT);
        }
        {
            int guard = 0;
            while (__hip_atomic_load(&flags[tid & 255], __ATOMIC_RELAXED,
                                     __HIP_MEMORY_SCOPE_AGENT) < (unsigned)(p + 1)) {
                if (++guard > (1 << 17)) break;  // hang insurance only
            }
        }
        asm volatile("" ::: "memory");
        __syncthreads();   // also protects LDS reuse next phase
    }

    // ---- epilogue ----
    if (use_hist) {
        // WG w computes out[16w .. 16w+16): 2x 1024-dot per t across 512 thr
        for (int i = 0; i < 16; ++i) {
            const int t = (wg << 4) + i;
            const float* hp = h2hist + (size_t)t * HID + (tid << 1);
            float hv0 = ld_agent(hp + 0), hv1 = ld_agent(hp + 1);
            float q0 = wo0.x * hv0 + wo0.y * hv1;
            float q1 = wo1.x * hv0 + wo1.y * hv1;
            #pragma unroll
            for (int m = 1; m < 64; m <<= 1) {
                q0 += __shfl_xor(q0, m);
                q1 += __shfl_xor(q1, m);
            }
            if (lane == 0) { red0[wave] = q0; red1[wave] = q1; }
            __syncthreads();
            if (tid == 0) {
                float o0 = bo0, o1 = bo1;
                #pragma unroll
                for (int w = 0; w < 8; ++w) { o0 += red0[w]; o1 += red1[w]; }
                out[2*t+0] = o0;
                out[2*t+1] = o1;
            }
            __syncthreads();
        }
    } else if (wg == 0) {
        // out[T-1]: h2(T-1) lives in slot TSTEPS&1 == 0
        const float* hp = h2buf + (TSTEPS & 1) * HID + (tid << 1);
        float hv0 = ld_agent(hp + 0), hv1 = ld_agent(hp + 1);
        float q0 = wo0.x * hv0 + wo0.y * hv1;
        float q1 = wo1.x * hv0 + wo1.y * hv1;
        #pragma unroll
        for (int m = 1; m < 64; m <<= 1) {
            q0 += __shfl_xor(q0, m);
            q1 += __shfl_xor(q1, m);
        }
        if (lane == 0) { red0[wave] = q0; red1[wave] = q1; }
        __syncthreads();
        if (tid == 0) {
            float o0 = bo0, o1 = bo1;
            #pragma unroll
            for (int w = 0; w < 8; ++w) { o0 += red0[w]; o1 += red1[w]; }
            out[2*(TSTEPS-1)+0] = o0;
            out[2*(TSTEPS-1)+1] = o1;
        }
    }
}

extern "C" void kernel_launch(void* const* d_in, const int* in_sizes, int n_in,
                              void* d_out, int out_size, void* d_ws, size_t ws_size,
                              hipStream_t stream)
{
    const float* x    = (const float*)d_in[0];
    const float* Wih1 = (const float*)d_in[1];
    const float* Whh1 = (const float*)d_in[2];
    const float* bih1 = (const float*)d_in[3];
    const float* bhh1 = (const float*)d_in[4];
    const float* Wih2 = (const float*)d_in[5];
    const float* Whh2 = (const float*)d_in[6];
    const float* bih2 = (const float*)d_in[7];
    const float* bhh2 = (const float*)d_in[8];
    const float* Wout = (const float*)d_in[9];
    const float* bout = (const float*)d_in[10];
    float* out = (float*)d_out;
    float* ws  = (float*)d_ws;

    const int use_hist = (ws_size >= WS_HIST_BYTES) ? 1 : 0;

    // zero h-state + barrier flags (ws re-poisoned 0xAA before every call)
    hipMemsetAsync(d_ws, 0, WS_ZERO_BYTES, stream);

    hipLaunchKernelGGL(lstm_persistent, dim3(NWG), dim3(TPB), 0, stream,
                       x, Wih1, Whh1, bih1, bhh1,
                       Wih2, Whh2, bih2, bhh2,
                       Wout, bout, out, ws, use_hist);
}

// Round 6
// 17331.233 us; speedup vs baseline: 1.6366x; 1.4762x over previous
//
#include <hip/hip_runtime.h>
#include <math.h>

// LSTM_53171695124900: 2-layer LSTM, H=1024, I=64, O=2, T=4096.
// Persistent kernel, 256 WGs x 512 threads (1 WG/CU, 2 waves/SIMD).
// Round-6 changes vs round-5 (25.6ms, 6.3us/phase):
//  1) NO grid barrier. Cross-WG h exchange via tagged 8B pairs
//     {f32 value, u32 phase}: consumers poll exactly the 16B they need
//     until tags match -> sync+data = ONE IC round trip (was 3: vmcnt,
//     flag publish/poll, then h load). h1 = 2 tagged slots (parity);
//     h2 = tagged history rows (write-once; doubles as epilogue input).
//     Overwrite safety: producer reaches phase p+1 only after all WGs
//     published phase p (it polled their tags), so tag p-1 data is dead
//     before it's overwritten. Exact == tag match rejects 0xAA poison.
//  2) Weight keepalive asm INSIDE the loop: r2-r5 all spilled the weights
//     despite entry pins + occupancy attrs (VGPR 140/92/84/92 < 96 floats);
//     in-loop "+v" pins make spill+reload strictly worse than residency.

#define HID 1024
#define DIN 64
#define TSTEPS 4096
#define NWG 256
#define TPB 512

typedef unsigned long long u64;
typedef unsigned int u32;

// ws layout in u64 (8B tagged pairs):
//   [0, 2048)                 : h1 pairs, 2 slots x 1024
//   [2048, 2048 + 4097*1024)  : h2 pairs; hist mode = row per phase,
//                               fallback mode = rows (phase & 1)
#define H2_OFF 2048
#define WS_NEED_U64 (2048ull + 4097ull * 1024ull)
#define WS_NEED_BYTES (WS_NEED_U64 * 8ull)
#define WS_ZERO_BYTES 32768   // h1 slots (16KB) + h2 rows 0..1 (16KB)

__device__ __forceinline__ float sigmoid_f(float v) {
    return 1.0f / (1.0f + __expf(-v));
}
__device__ __forceinline__ float tanh_f(float v) {
    return 2.0f / (1.0f + __expf(-2.0f * v)) - 1.0f;
}

// relaxed agent-scope 8B atomics: coherent at IC, no cache-maintenance insts
__device__ __forceinline__ void st_pair(u64* p, float h, u32 tag) {
    u64 pk = ((u64)tag << 32) | (u64)__float_as_uint(h);
    __hip_atomic_store(p, pk, __ATOMIC_RELAXED, __HIP_MEMORY_SCOPE_AGENT);
}
__device__ __forceinline__ u64 ld_pair(const u64* p) {
    return __hip_atomic_load(p, __ATOMIC_RELAXED, __HIP_MEMORY_SCOPE_AGENT);
}
#define PTAG(v) ((u32)((v) >> 32))
#define PVAL(v) (__uint_as_float((u32)(v)))

#define PIN4(v) asm volatile("" : "+v"((v).x), "+v"((v).y), "+v"((v).z), "+v"((v).w))
#define PIN_ALL() do { \
    PIN4(w1a); PIN4(w1b); PIN4(w1c); PIN4(w1d); \
    PIN4(w1e); PIN4(w1f); PIN4(w1g); PIN4(w1h); \
    PIN4(w2a); PIN4(w2b); PIN4(w2c); PIN4(w2d); \
    PIN4(w2e); PIN4(w2f); PIN4(w2g); PIN4(w2h); \
    PIN4(w3a); PIN4(w3b); PIN4(w3c); PIN4(w3d); \
    PIN4(w3e); PIN4(w3f); PIN4(w3g); PIN4(w3h); \
} while (0)

#define GSTEP(o, W1, W2, W3) do {                                   \
    float4 hv = *(const float4*)(hb + (o));                         \
    a0 = fmaf((W1).x, hv.x, a0); a1 = fmaf((W1).y, hv.y, a1);       \
    a2 = fmaf((W1).z, hv.z, a2); a3 = fmaf((W1).w, hv.w, a3);       \
    e0 = fmaf((W2).x, hv.x, e0); e1 = fmaf((W2).y, hv.y, e1);       \
    e2 = fmaf((W2).z, hv.z, e2); e3 = fmaf((W2).w, hv.w, e3);       \
    float4 gv = *(const float4*)(gb + (o));                         \
    e0 = fmaf((W3).x, gv.x, e0); e1 = fmaf((W3).y, gv.y, e1);       \
    e2 = fmaf((W3).z, gv.z, e2); e3 = fmaf((W3).w, gv.w, e3);       \
} while (0)

__global__ void
__attribute__((amdgpu_flat_work_group_size(TPB, TPB), amdgpu_waves_per_eu(2, 2)))
lstm_persistent(
    const float* __restrict__ x,
    const float* __restrict__ Wih1, const float* __restrict__ Whh1,
    const float* __restrict__ bih1, const float* __restrict__ bhh1,
    const float* __restrict__ Wih2, const float* __restrict__ Whh2,
    const float* __restrict__ bih2, const float* __restrict__ bhh2,
    const float* __restrict__ Wout, const float* __restrict__ bout,
    float* __restrict__ out, u64* __restrict__ ws, int use_hist)
{
    const int wg   = blockIdx.x;          // 0..255
    const int tid  = threadIdx.x;         // 0..511
    const int wave = tid >> 6;            // 0..7
    const int lane = tid & 63;
    const int gate = tid >> 7;            // 0..3 (i,f,g,o)
    const int rsub = (tid >> 5) & 3;      // local unit 0..3
    const int c    = tid & 31;            // k-chunk 0..31
    const int row  = gate * HID + (wg << 2) + rsub;   // gate row in [0,4096)
    const int kbase = c << 5;

    u64* h1t = ws;
    u64* h2t = ws + H2_OFF;

    // ---- persistent register weights: 24 named float4 SSA values ----
    const float4* p1 = (const float4*)(Whh1 + (size_t)row * HID + kbase);
    const float4* p2 = (const float4*)(Wih2 + (size_t)row * HID + kbase);
    const float4* p3 = (const float4*)(Whh2 + (size_t)row * HID + kbase);
    float4 w1a = p1[0], w1b = p1[1], w1c = p1[2], w1d = p1[3];
    float4 w1e = p1[4], w1f = p1[5], w1g = p1[6], w1h = p1[7];
    float4 w2a = p2[0], w2b = p2[1], w2c = p2[2], w2d = p2[3];
    float4 w2e = p2[4], w2f = p2[5], w2g = p2[6], w2h = p2[7];
    float4 w3a = p3[0], w3b = p3[1], w3c = p3[2], w3d = p3[3];
    float4 w3e = p3[4], w3f = p3[5], w3g = p3[6], w3h = p3[7];
    PIN_ALL();

    const float2 wx = *(const float2*)(Wih1 + (size_t)row * DIN + (c << 1));
    const float bsum1 = bih1[row] + bhh1[row];
    const float bsum2 = bih2[row] + bhh2[row];

    __shared__ __align__(16) float h1s[1152];
    __shared__ __align__(16) float h2s[1152];
    __shared__ float g1[4][4], g2[4][4];
    __shared__ float c1s[4], c2s[4];
    __shared__ float red0[8], red1[8];
    if (tid < 4) { c1s[tid] = 0.0f; c2s[tid] = 0.0f; }

    // element e=2*tid lands at 36*(e>>5) + (e&31); read base 36*c
    const int sdst = 36 * (tid >> 4) + ((tid << 1) & 31);
    const int sbase = 36 * c;

    for (int p = 0; p <= TSTEPS; ++p) {
        // ---- tagged poll: h1(p-1) from slot p&1 (tag p);
        //      h2(p-2) from row p-1 (hist) / (p-1)&1 (fallback), tag p (p>=2)
        const u64* h1p = h1t + (size_t)(p & 1) * 1024 + (tid << 1);
        const int h2row_c = (p > 0) ? (use_hist ? (p - 1) : ((p - 1) & 1)) : 0;
        const u64* h2p = h2t + (size_t)h2row_c * 1024 + (tid << 1);
        const u32 want1 = (u32)p;
        const u32 want2 = (p >= 2) ? (u32)p : 0u;

        const int tx = (p < TSTEPS) ? p : 0;
        const float2 xv = *(const float2*)(x + (size_t)tx * DIN + (c << 1));

        u64 v1a, v1b, v2a, v2b;
        {
            int guard = 0;
            for (;;) {
                v1a = ld_pair(h1p);     v1b = ld_pair(h1p + 1);
                v2a = ld_pair(h2p);     v2b = ld_pair(h2p + 1);
                if ((PTAG(v1a) == want1) & (PTAG(v1b) == want1) &
                    (PTAG(v2a) == want2) & (PTAG(v2b) == want2)) break;
                if (++guard > (1 << 15)) break;  // hang insurance only
            }
        }
        float sa0 = PVAL(v1a), sa1 = PVAL(v1b);
        float sb0 = PVAL(v2a), sb1 = PVAL(v2b);

        // in-loop keepalive: weights must be VGPR-resident here every phase
        PIN_ALL();

        *(float2*)(h1s + sdst) = make_float2(sa0, sa1);
        *(float2*)(h2s + sdst) = make_float2(sb0, sb1);

        // ---- fallback out-path (no hist workspace): WG0, out(p-2) ----
        if (!use_hist && wg == 0 && p >= 2) {
            const float2 wo0 = *(const float2*)(Wout + (tid << 1));
            const float2 wo1 = *(const float2*)(Wout + HID + (tid << 1));
            float q0 = wo0.x * sb0 + wo0.y * sb1;
            float q1 = wo1.x * sb0 + wo1.y * sb1;
            #pragma unroll
            for (int m = 1; m < 64; m <<= 1) {
                q0 += __shfl_xor(q0, m);
                q1 += __shfl_xor(q1, m);
            }
            if (lane == 0) { red0[wave] = q0; red1[wave] = q1; }
            __syncthreads();
            if (tid == 0) {
                float o0 = bout[0], o1 = bout[1];
                #pragma unroll
                for (int w = 0; w < 8; ++w) { o0 += red0[w]; o1 += red1[w]; }
                out[2*(p-2)+0] = o0;
                out[2*(p-2)+1] = o1;
            }
        }
        __syncthreads();

        // ---- dots: a* = Whh1 . h1prev (+x)        [layer 1, t=p]
        //            e* = Wih2 . h1prev + Whh2 . h2prev [layer 2, t=p-1]
        float a0=0.f, a1=0.f, a2=0.f, a3=0.f;
        float e0=0.f, e1=0.f, e2=0.f, e3=0.f;
        const float* hb = h1s + sbase;
        const float* gb = h2s + sbase;
        GSTEP(0,  w1a, w2a, w3a);
        GSTEP(4,  w1b, w2b, w3b);
        GSTEP(8,  w1c, w2c, w3c);
        GSTEP(12, w1d, w2d, w3d);
        GSTEP(16, w1e, w2e, w3e);
        GSTEP(20, w1f, w2f, w3f);
        GSTEP(24, w1g, w2g, w3g);
        GSTEP(28, w1h, w2h, w3h);
        a0 = fmaf(wx.x, xv.x, a0);
        a1 = fmaf(wx.y, xv.y, a1);

        float accA = (a0 + a1) + (a2 + a3);
        float accB = (e0 + e1) + (e2 + e3);
        accA += __shfl_xor(accA, 1);   accB += __shfl_xor(accB, 1);
        accA += __shfl_xor(accA, 2);   accB += __shfl_xor(accB, 2);
        accA += __shfl_xor(accA, 4);   accB += __shfl_xor(accB, 4);
        accA += __shfl_xor(accA, 8);   accB += __shfl_xor(accB, 8);
        accA += __shfl_xor(accA, 16);  accB += __shfl_xor(accB, 16);
        if (c == 0) {
            float vA = accA + bsum1;
            float vB = accB + bsum2;
            g1[gate][rsub] = (gate == 2) ? tanh_f(vA) : sigmoid_f(vA);
            g2[gate][rsub] = (gate == 2) ? tanh_f(vB) : sigmoid_f(vB);
        }
        __syncthreads();

        // ---- state updates + tagged publication (no barrier) ----
        if (p < TSTEPS && tid < 4) {
            float iv = g1[0][tid], fv = g1[1][tid];
            float gv = g1[2][tid], ov = g1[3][tid];
            float cn = fv * c1s[tid] + iv * gv;
            c1s[tid] = cn;
            st_pair(h1t + (size_t)((p + 1) & 1) * 1024 + (wg << 2) + tid,
                    ov * tanh_f(cn), (u32)(p + 1));
        }
        if (p >= 1 && tid >= 4 && tid < 8) {
            int u = tid - 4;
            float iv = g2[0][u], fv = g2[1][u];
            float gv = g2[2][u], ov = g2[3][u];
            float cn = fv * c2s[u] + iv * gv;
            c2s[u] = cn;
            const int wr = use_hist ? p : (p & 1);
            st_pair(h2t + (size_t)wr * 1024 + (wg << 2) + u,
                    ov * tanh_f(cn), (u32)(p + 1));
        }
        // no grid barrier: next phase's poll is the synchronization
    }

    // ---- epilogue ----
    if (use_hist) {
        const float2 wo0 = *(const float2*)(Wout + (tid << 1));
        const float2 wo1 = *(const float2*)(Wout + HID + (tid << 1));
        const float bo0 = bout[0], bo1 = bout[1];
        for (int i = 0; i < 16; ++i) {
            const int t = (wg << 4) + i;
            const u64* hp = h2t + (size_t)(t + 1) * 1024 + (tid << 1);
            const u32 want = (u32)(t + 2);
            u64 va, vb; int guard = 0;
            for (;;) {
                va = ld_pair(hp); vb = ld_pair(hp + 1);
                if ((PTAG(va) == want) && (PTAG(vb) == want)) break;
                if (++guard > (1 << 15)) break;
            }
            float h0 = PVAL(va), h1v = PVAL(vb);
            float q0 = wo0.x * h0 + wo0.y * h1v;
            float q1 = wo1.x * h0 + wo1.y * h1v;
            #pragma unroll
            for (int m = 1; m < 64; m <<= 1) {
                q0 += __shfl_xor(q0, m);
                q1 += __shfl_xor(q1, m);
            }
            if (lane == 0) { red0[wave] = q0; red1[wave] = q1; }
            __syncthreads();
            if (tid == 0) {
                float o0 = bo0, o1 = bo1;
                #pragma unroll
                for (int w = 0; w < 8; ++w) { o0 += red0[w]; o1 += red1[w]; }
                out[2*t+0] = o0;
                out[2*t+1] = o1;
            }
            __syncthreads();
        }
    } else if (wg == 0) {
        // final out[T-1]: h2(T-1) written phase TSTEPS -> row TSTEPS&1 = 0,
        // tag TSTEPS+1
        const float2 wo0 = *(const float2*)(Wout + (tid << 1));
        const float2 wo1 = *(const float2*)(Wout + HID + (tid << 1));
        const u64* hp = h2t + (size_t)(TSTEPS & 1) * 1024 + (tid << 1);
        const u32 want = (u32)(TSTEPS + 1);
        u64 va, vb; int guard = 0;
        for (;;) {
            va = ld_pair(hp); vb = ld_pair(hp + 1);
            if ((PTAG(va) == want) && (PTAG(vb) == want)) break;
            if (++guard > (1 << 15)) break;
        }
        float h0 = PVAL(va), h1v = PVAL(vb);
        float q0 = wo0.x * h0 + wo0.y * h1v;
        float q1 = wo1.x * h0 + wo1.y * h1v;
        #pragma unroll
        for (int m = 1; m < 64; m <<= 1) {
            q0 += __shfl_xor(q0, m);
            q1 += __shfl_xor(q1, m);
        }
        if (lane == 0) { red0[wave] = q0; red1[wave] = q1; }
        __syncthreads();
        if (tid == 0) {
            float o0 = bout[0], o1 = bout[1];
            #pragma unroll
            for (int w = 0; w < 8; ++w) { o0 += red0[w]; o1 += red1[w]; }
            out[2*(TSTEPS-1)+0] = o0;
            out[2*(TSTEPS-1)+1] = o1;
        }
    }
}

extern "C" void kernel_launch(void* const* d_in, const int* in_sizes, int n_in,
                              void* d_out, int out_size, void* d_ws, size_t ws_size,
                              hipStream_t stream)
{
    const float* x    = (const float*)d_in[0];
    const float* Wih1 = (const float*)d_in[1];
    const float* Whh1 = (const float*)d_in[2];
    const float* bih1 = (const float*)d_in[3];
    const float* bhh1 = (const float*)d_in[4];
    const float* Wih2 = (const float*)d_in[5];
    const float* Whh2 = (const float*)d_in[6];
    const float* bih2 = (const float*)d_in[7];
    const float* bhh2 = (const float*)d_in[8];
    const float* Wout = (const float*)d_in[9];
    const float* bout = (const float*)d_in[10];
    float* out = (float*)d_out;
    u64*   ws  = (u64*)d_ws;

    const int use_hist = (ws_size >= WS_NEED_BYTES) ? 1 : 0;

    // zero h1 slots + h2 rows 0..1 (ws re-poisoned 0xAA before every call;
    // poison can never equal a wanted tag, so un-zeroed hist rows are safe)
    hipMemsetAsync(d_ws, 0, WS_ZERO_BYTES, stream);

    hipLaunchKernelGGL(lstm_persistent, dim3(NWG), dim3(TPB), 0, stream,
                       x, Wih1, Whh1, bih1, bhh1,
                       Wih2, Whh2, bih2, bhh2,
                       Wout, bout, out, ws, use_hist);
}